// Round 4
// baseline (657.603 us; speedup 1.0000x reference)
//
#include <hip/hip_runtime.h>

// One WAVE (64 lanes) per batch element; 4 independent waves per 256-thread
// block (wave w handles b = 4*blockIdx + w). ZERO LDS, ZERO barriers.
//
// Neuron ownership is chosen so ALL big global accesses are coalesced
// q-layout (q = lane + 64k over float4 quads):
//   quad q -> row h = q>>2 = (lane>>2) + 16k, feature-quad j = lane&3.
// After an intra-quad butterfly, lane t owns hidden neurons
//   h0 = (t>>2) + 32*(t&3),  h1 = h0 + 16.
// W_in is read twice from global (GEMV head + update tail), both coalesced;
// the second read is partially L2-hot. This trades ~+40MB fetch for dropping
// the 8KB LDS staging that capped occupancy at 14 waves/CU in R2.

namespace {

constexpr int F = 16;
constexpr int H = 128;
constexpr int G = 4;
constexpr int S = 20;

typedef float vfloat4 __attribute__((ext_vector_type(4)));  // native vec for NT stores

__device__ __forceinline__ float clip3(float x) {
    return fminf(fmaxf(x, -3.0f), 3.0f);
}

__device__ __forceinline__ void nt_store4(float4 v, float4* p) {
    vfloat4 x = {v.x, v.y, v.z, v.w};
    __builtin_nontemporal_store(x, (vfloat4*)p);
}

// hrate[h] lives in (hr0,hr1) of lane 4*(h&15) + ((h>>4)>>1); reg = (h>>4)&1.
__device__ __forceinline__ float hrate_at(int h, float hr0, float hr1) {
    int m   = h >> 4;
    int src = ((h & 15) << 2) | (m >> 1);
    float a = __shfl(hr0, src, 64);
    float b = __shfl(hr1, src, 64);
    return (m & 1) ? b : a;
}

__global__ __launch_bounds__(256, 7)
void spiking_critic_kernel(
    const float* __restrict__ energy,
    const float* __restrict__ threat,
    const float* __restrict__ food_visible,
    const int*   __restrict__ goal,
    const int*   __restrict__ prev_goal,
    const float* __restrict__ DA,
    const float* __restrict__ NA,
    const float* __restrict__ reward,
    const float* __restrict__ cls_probs,
    const float* __restrict__ W_in_w,
    const float* __restrict__ W_in_b,
    const float* __restrict__ W_out_w,
    const float* __restrict__ W_out_b,
    const float* __restrict__ hv_in,
    const float* __restrict__ hu_in,
    const float* __restrict__ hrate_in,
    const float* __restrict__ vv_in,
    const float* __restrict__ vu_in,
    const float* __restrict__ vrate_in,
    const float* __restrict__ elig_in,
    const float* __restrict__ elig_out,
    const float* __restrict__ prev_values,
    const float* __restrict__ prev_features,
    const float* __restrict__ noise,
    float* __restrict__ out_values,
    float* __restrict__ out_td,
    float* __restrict__ out_hidden,
    float* __restrict__ out_Win,
    float* __restrict__ out_Wout,
    float* __restrict__ out_ein,
    float* __restrict__ out_eout,
    int nB)
{
    const int t = threadIdx.x & 63;
    int b = blockIdx.x * 4 + (threadIdx.x >> 6);
    b = __builtin_amdgcn_readfirstlane(b);      // wave-uniform -> s_loads below
    if (b >= nB) return;

    const int j = t & 3;                        // feature-quad of this lane

    // ---- per-b scalars (all SGPR) ----
    const float e_b   = energy[b];
    const float thr_b = threat[b];
    const float fv_b  = food_visible[b];
    const int   gl_b  = goal[b];
    const float da_b  = DA[b];
    const float na_b  = NA[b];
    const float c0 = cls_probs[(size_t)b * 5 + 0];
    const float c1 = cls_probs[(size_t)b * 5 + 1];
    const float c2 = cls_probs[(size_t)b * 5 + 2];
    const float c3 = cls_probs[(size_t)b * 5 + 3];
    const float c4 = cls_probs[(size_t)b * 5 + 4];
    const float en100 = e_b / 100.0f;

    // feature quads (scalar values, per-lane select by j)
    // q0 = {e/100, threat, food, 1-e/100}
    // q1 = one-hot(goal)
    // q2 = {cls0..3}
    // q3 = {cls4, DA, NA, hunger}
    const float g0 = (gl_b == 0) ? 1.0f : 0.0f;
    const float g1 = (gl_b == 1) ? 1.0f : 0.0f;
    const float g2 = (gl_b == 2) ? 1.0f : 0.0f;
    const float g3 = (gl_b == 3) ? 1.0f : 0.0f;
    const float hunger = fmaxf(0.0f, 0.5f - en100);

    const bool j1 = (j & 1) != 0;
    const bool j2 = (j & 2) != 0;
    float fx = j2 ? (j1 ? c4     : c0) : (j1 ? g0 : en100);
    float fy = j2 ? (j1 ? da_b   : c1) : (j1 ? g1 : thr_b);
    float fz = j2 ? (j1 ? na_b   : c2) : (j1 ? g2 : fv_b);
    float fw = j2 ? (j1 ? hunger : c3) : (j1 ? g3 : 1.0f - en100);

    // ---- I_in: coalesced q-layout GEMV + intra-quad butterfly ----
    const float4* wi4 = (const float4*)(W_in_w + (size_t)b * (H * F));
    float p[8];
    #pragma unroll
    for (int k = 0; k < 8; ++k) {
        float4 w = wi4[t + 64 * k];
        p[k] = w.x * fx + w.y * fy + w.z * fz + w.w * fw;
    }
    #pragma unroll
    for (int k = 0; k < 8; ++k) {
        p[k] += __shfl_xor(p[k], 1, 64);
        p[k] += __shfl_xor(p[k], 2, 64);
        p[k] += W_in_b[(size_t)b * H + (t >> 2) + 16 * k];   // bias
    }
    // lane t owns k0 = 2j, k1 = 2j+1  ->  h0 = (t>>2)+32j, h1 = h0+16
    const int h0 = (t >> 2) + 32 * j;
    const int h1 = h0 + 16;
    float Ir0a = j1 ? p[2] : p[0], Ir0b = j1 ? p[6] : p[4];
    float Iraw0 = j2 ? Ir0b : Ir0a;
    float Ir1a = j1 ? p[3] : p[1], Ir1b = j1 ? p[7] : p[5];
    float Iraw1 = j2 ? Ir1b : Ir1a;

    float a = fabsf(Iraw0) + fabsf(Iraw1);
    #pragma unroll
    for (int m = 32; m >= 1; m >>= 1) a += __shfl_xor(a, m, 64);
    const float inorm = 5.0f / (a * (1.0f / 128.0f) + 1e-8f);
    const float Iin0 = Iraw0 * inorm;
    const float Iin1 = Iraw1 * inorm;

    // ---- W_out columns for owned neurons + output-layer state (scalar) ----
    float wc0[G], wc1[G], wob[G], vv[G], vu[G], vr[G];
    #pragma unroll
    for (int g = 0; g < G; ++g) {
        wc0[g] = W_out_w[(size_t)b * (G * H) + g * H + h0];
        wc1[g] = W_out_w[(size_t)b * (G * H) + g * H + h1];
        wob[g] = W_out_b[(size_t)b * G + g];
        vv[g]  = vv_in[(size_t)b * G + g];
        vu[g]  = vu_in[(size_t)b * G + g];
        vr[g]  = vrate_in[(size_t)b * G + g];
    }

    // ---- hidden state for owned neurons ----
    float hv0 = hv_in[(size_t)b * H + h0], hv1 = hv_in[(size_t)b * H + h1];
    float hu0 = hu_in[(size_t)b * H + h0], hu1 = hu_in[(size_t)b * H + h1];
    float hr0 = hrate_in[(size_t)b * H + h0], hr1 = hrate_in[(size_t)b * H + h1];

    // ---- rolling depth-2 noise prefetch (4 regs instead of 40) ----
    float nb0[2], nb1[2];
    nb0[0] = noise[((size_t)0 * nB + b) * H + h0];
    nb1[0] = noise[((size_t)0 * nB + b) * H + h1];
    nb0[1] = noise[((size_t)1 * nB + b) * H + h0];
    nb1[1] = noise[((size_t)1 * nB + b) * H + h1];

    float hsp0 = 0.0f, hsp1 = 0.0f;
    float vals[G] = {0.f, 0.f, 0.f, 0.f};

    #pragma unroll
    for (int s = 0; s < S; ++s) {
        const float n0 = nb0[s & 1];
        const float n1 = nb1[s & 1];
        if (s + 2 < S) {
            nb0[s & 1] = noise[((size_t)(s + 2) * nB + b) * H + h0];
            nb1[s & 1] = noise[((size_t)(s + 2) * nB + b) * H + h1];
        }
        {   // hidden neuron h0
            float I  = Iin0 + 0.3f * n0;
            float vn = hv0 + (0.04f * hv0 * hv0 + 5.0f * hv0 + 140.0f - hu0 + I);
            float un = hu0 + 0.02f * (0.2f * hv0 - hu0);
            float sp = (vn >= 30.0f) ? 1.0f : 0.0f;
            hv0 = (sp > 0.0f) ? -65.0f : vn;
            hu0 = un + sp * 8.0f;
            hr0 = 0.9f * hr0 + 0.1f * sp;
            hsp0 += sp;
        }
        {   // hidden neuron h1
            float I  = Iin1 + 0.3f * n1;
            float vn = hv1 + (0.04f * hv1 * hv1 + 5.0f * hv1 + 140.0f - hu1 + I);
            float un = hu1 + 0.02f * (0.2f * hv1 - hu1);
            float sp = (vn >= 30.0f) ? 1.0f : 0.0f;
            hv1 = (sp > 0.0f) ? -65.0f : vn;
            hu1 = un + sp * 8.0f;
            hr1 = 0.9f * hr1 + 0.1f * sp;
            hsp1 += sp;
        }

        // I_out[g]: per-lane partials + full-wave butterfly (all lanes get sums)
        float p0 = wc0[0] * hr0 + wc1[0] * hr1;
        float p1 = wc0[1] * hr0 + wc1[1] * hr1;
        float p2 = wc0[2] * hr0 + wc1[2] * hr1;
        float p3 = wc0[3] * hr0 + wc1[3] * hr1;
        #pragma unroll
        for (int m = 32; m >= 1; m >>= 1) {
            p0 += __shfl_xor(p0, m, 64);
            p1 += __shfl_xor(p1, m, 64);
            p2 += __shfl_xor(p2, m, 64);
            p3 += __shfl_xor(p3, m, 64);
        }
        vals[0] = p0 + wob[0];
        vals[1] = p1 + wob[1];
        vals[2] = p2 + wob[2];
        vals[3] = p3 + wob[3];

        // output Izhikevich step, redundantly in all lanes
        float m4 = 0.25f * (fabsf(vals[0]) + fabsf(vals[1])
                          + fabsf(vals[2]) + fabsf(vals[3]));
        float onorm = 4.0f / (m4 + 1e-8f);
        #pragma unroll
        for (int g = 0; g < G; ++g) {
            float Io = vals[g] * onorm;
            float vn = vv[g] + (0.04f * vv[g] * vv[g] + 5.0f * vv[g] + 140.0f - vu[g] + Io);
            float un = vu[g] + 0.02f * (0.2f * vv[g] - vu[g]);
            float sp = (vn >= 30.0f) ? 1.0f : 0.0f;
            vv[g] = (sp > 0.0f) ? -65.0f : vn;
            vu[g] = un + sp * 8.0f;
            vr[g] = 0.9f * vr[g] + 0.1f * sp;
        }
    }

    // ---- outputs: values (== last raw I_out), hidden_active, td ----
    if (t < G) {
        float v = (t == 0) ? vals[0] : (t == 1) ? vals[1] : (t == 2) ? vals[2] : vals[3];
        out_values[(size_t)b * G + t] = v;
    }
    unsigned long long mb0 = __ballot(hsp0 > 0.0f);
    unsigned long long mb1 = __ballot(hsp1 > 0.0f);
    float hidden = (float)(__popcll(mb0) + __popcll(mb1)) * (1.0f / 128.0f);

    float Vnow  = (gl_b == 0) ? vals[0] : (gl_b == 1) ? vals[1]
                : (gl_b == 2) ? vals[2] : vals[3];
    float Vprev = prev_values[(size_t)b * G + prev_goal[b]];
    float td = reward[b] + 0.95f * Vnow - Vprev;
    if (t == 0) {
        out_td[b]     = td;
        out_hidden[b] = hidden;
    }

    const float scale = 1e-3f * td * da_b;
    const bool  upd   = fabsf(td) > 1e-3f;

    // hrk[k] = hrate[(t>>2)+16k]  (quad-mates hold them)
    float hrk[8];
    #pragma unroll
    for (int jj = 0; jj < 4; ++jj) {
        int src = (t & ~3) + jj;
        hrk[2 * jj]     = __shfl(hr0, src, 64);
        hrk[2 * jj + 1] = __shfl(hr1, src, 64);
    }

    // ---- elig_in / W_in update: coalesced q-layout; W_in re-read (L2-hot) ----
    {
        const float4* ei4 = (const float4*)(elig_in + (size_t)b * (H * F));
        float4* oW = (float4*)(out_Win + (size_t)b * (H * F));
        float4* oE = (float4*)(out_ein + (size_t)b * (H * F));
        float4 pf = ((const float4*)(prev_features + (size_t)b * F))[j];
        #pragma unroll
        for (int k = 0; k < 8; ++k) {
            int q = t + 64 * k;
            float4 e = ei4[q];
            float4 w = wi4[q];
            float  hrv = hrk[k];
            float4 en;
            en.x = 0.9f * e.x + hrv * pf.x;
            en.y = 0.9f * e.y + hrv * pf.y;
            en.z = 0.9f * e.z + hrv * pf.z;
            en.w = 0.9f * e.w + hrv * pf.w;
            nt_store4(en, &oE[q]);
            float4 wn;
            if (upd) {
                wn.x = clip3(w.x + scale * en.x);
                wn.y = clip3(w.y + scale * en.y);
                wn.z = clip3(w.z + scale * en.z);
                wn.w = clip3(w.w + scale * en.w);
            } else {
                wn = w;
            }
            nt_store4(wn, &oW[q]);
        }
    }

    // ---- elig_out / W_out update: coalesced q-layout ----
    {
        const float4* eo4 = (const float4*)(elig_out + (size_t)b * (G * H));
        const float4* wo4 = (const float4*)(W_out_w + (size_t)b * (G * H));
        float4* oW = (float4*)(out_Wout + (size_t)b * (G * H));
        float4* oE = (float4*)(out_eout + (size_t)b * (G * H));
        #pragma unroll
        for (int k = 0; k < 2; ++k) {
            int q = t + 64 * k;
            int c = q & 31;
            float4 e = eo4[q];
            float4 w = wo4[q];
            float vrv = (k == 0) ? ((t < 32) ? vr[0] : vr[1])
                                 : ((t < 32) ? vr[2] : vr[3]);
            float4 hq;
            hq.x = hrate_at(4 * c + 0, hr0, hr1);
            hq.y = hrate_at(4 * c + 1, hr0, hr1);
            hq.z = hrate_at(4 * c + 2, hr0, hr1);
            hq.w = hrate_at(4 * c + 3, hr0, hr1);
            float4 en;
            en.x = 0.9f * e.x + vrv * hq.x;
            en.y = 0.9f * e.y + vrv * hq.y;
            en.z = 0.9f * e.z + vrv * hq.z;
            en.w = 0.9f * e.w + vrv * hq.w;
            nt_store4(en, &oE[q]);
            float4 wn;
            if (upd) {
                wn.x = clip3(w.x + scale * en.x);
                wn.y = clip3(w.y + scale * en.y);
                wn.z = clip3(w.z + scale * en.z);
                wn.w = clip3(w.w + scale * en.w);
            } else {
                wn = w;
            }
            nt_store4(wn, &oW[q]);
        }
    }
}

} // namespace

extern "C" void kernel_launch(void* const* d_in, const int* in_sizes, int n_in,
                              void* d_out, int out_size, void* d_ws, size_t ws_size,
                              hipStream_t stream) {
    const int nB = in_sizes[0];          // 8192

    float* out        = (float*)d_out;   // outputs concatenated flat
    float* out_values = out;
    float* out_td     = out_values + (size_t)nB * G;
    float* out_hidden = out_td + nB;
    float* out_Win    = out_hidden + nB;
    float* out_Wout   = out_Win + (size_t)nB * H * F;
    float* out_ein    = out_Wout + (size_t)nB * G * H;
    float* out_eout   = out_ein + (size_t)nB * H * F;

    const int nBlocks = (nB + 3) / 4;    // 4 waves (4 batch elems) per block
    spiking_critic_kernel<<<dim3(nBlocks), dim3(256), 0, stream>>>(
        (const float*)d_in[0],  (const float*)d_in[1],  (const float*)d_in[2],
        (const int*)  d_in[3],  (const int*)  d_in[4],
        (const float*)d_in[5],  (const float*)d_in[6],  (const float*)d_in[7],
        (const float*)d_in[8],  (const float*)d_in[9],  (const float*)d_in[10],
        (const float*)d_in[11], (const float*)d_in[12], (const float*)d_in[13],
        (const float*)d_in[14], (const float*)d_in[15], (const float*)d_in[16],
        (const float*)d_in[17], (const float*)d_in[18], (const float*)d_in[19],
        (const float*)d_in[20], (const float*)d_in[21], (const float*)d_in[22],
        (const float*)d_in[23],
        out_values, out_td, out_hidden, out_Win, out_Wout, out_ein, out_eout,
        nB);
}